// Round 20
// baseline (86.156 us; speedup 1.0000x reference)
//
#include <hip/hip_runtime.h>
#include <cstdint>
#include <cstddef>

#define LRALPHA 0.1f
static constexpr int NR = 8192;      // N and Na
static constexpr int EF = 256;
static constexpr int IN_F = 512;
static constexpr int OUT_F = 512;
static constexpr int KP2 = 1024;     // fp16 split-2, k'-interleaved [ah,al]
static constexpr int NCH = 128;      // chunks for column scans
static constexpr int CHR = 64;       // rows per chunk (NCH*CHR = 8192)

typedef __attribute__((ext_vector_type(8))) _Float16 f16x8;
typedef __attribute__((ext_vector_type(4))) float f32x4;

// ---- fused prep: s1/s2 dots (blocks 0..4095) + B pack ----
__global__ __launch_bounds__(256) void k_prep(const float* __restrict__ feat_edge,
                                              const float* __restrict__ feat_edge_a,
                                              const float* __restrict__ att,
                                              const float* __restrict__ W,
                                              float* __restrict__ s1,
                                              float* __restrict__ s2,
                                              short* __restrict__ B3t) {
  int b = blockIdx.x;
  if (b < 4096) {
    int vrow = b * 4 + (threadIdx.x >> 6);
    int lane = threadIdx.x & 63;
    const float* feat; const float* av; float* outp; int row;
    if (vrow < NR) { row = vrow; feat = feat_edge; av = att; outp = s1; }
    else { row = vrow - NR; feat = feat_edge_a; av = att + EF; outp = s2; }
    float4 f = reinterpret_cast<const float4*>(feat + (size_t)row * EF)[lane];
    float4 a = reinterpret_cast<const float4*>(av)[lane];
    float d = f.x * a.x + f.y * a.y + f.z * a.z + f.w * a.w;
#pragma unroll
    for (int off = 32; off > 0; off >>= 1) d += __shfl_xor(d, off);
    if (lane == 0) outp[row] = d;
  } else {
    int i = (b - 4096) * 256 + threadIdx.x;  // < 512*512
    int n = i >> 9, k = i & 511;
    float x = W[(size_t)k * OUT_F + n];
    _Float16 h = (_Float16)x;
    unsigned short u = __builtin_bit_cast(unsigned short, h);
    unsigned int w = (unsigned int)u | ((unsigned int)u << 16);
    *reinterpret_cast<unsigned int*>(B3t + (size_t)n * KP2 + 2 * k) = w;
  }
}

// ---- Wh = split2(A) @ B3t^T : 128x128 tile, BK'=128, dbuf 128KB, 8 iters, 1 block/CU
// Barrier-iters law (R2..R16): time ~= per-CU-barrier-iters x ~0.7us. 16 -> 8.
struct SReg8 { float4 a[8]; int4 b[8]; };

__device__ __forceinline__ int swz(int row, int slot) {
  return (row & ~7) | ((row & 7) ^ (slot & 7));
}

__global__ __launch_bounds__(256, 1) void k_gemm(const float* __restrict__ A,
                                                 const short* __restrict__ B3t,
                                                 float* __restrict__ Wh) {
  // per buffer: [slot=k'/8 (16)][row (128)][8 f16] = 16384 shorts = 32KB; A+B dbuf = 128KB
  __shared__ short lA[2][16384];
  __shared__ short lB[2][16384];
  const int tid = threadIdx.x;
  const int wid = tid >> 6, lane = tid & 63;
  const int wr = wid >> 1, wc = wid & 1;
  int bid = blockIdx.x;                       // 0..255
  int xcd = bid & 7, loc = bid >> 3;          // 32 tiles per XCD
  int mb = (xcd << 3) | (loc >> 2), nb = loc & 3;   // XCD band: 2MB A + 1MB B L2-resident
  const int m0 = mb * 128, n0 = nb * 128;
  const int fr = lane & 15, g = lane >> 4;

  // staging: 2 threads/row; thread (srow=tid>>1, h=tid&1) covers k' [h*64, h*64+64)
  const int srow = tid >> 1, h = tid & 1;
  const float* gA = A + (size_t)(m0 + srow) * IN_F + h * 32;   // 32 real k per iter
  const short* gB = B3t + (size_t)(n0 + srow) * KP2 + h * 64;  // 64 k' per iter
  int wOf[8];
#pragma unroll
  for (int j = 0; j < 8; ++j) {
    int s = h * 8 + j;
    wOf[j] = s * 1024 + swz(srow, s) * 8;
  }

  f32x4 acc[4][4] = {};

  auto loadR = [&](SReg8& s, int t) {
    const float* pa = gA + t * 64;
#pragma unroll
    for (int j = 0; j < 8; ++j)
      s.a[j] = *reinterpret_cast<const float4*>(pa + j * 4);
    const short* pb = gB + t * 128;
#pragma unroll
    for (int j = 0; j < 8; ++j)
      s.b[j] = *reinterpret_cast<const int4*>(pb + j * 8);
  };

  auto cvt4 = [](float4 p) -> int4 {  // 4 f32 -> 4 dwords of [ah | al]
    float xs[4] = {p.x, p.y, p.z, p.w};
    int out[4];
#pragma unroll
    for (int e = 0; e < 4; ++e) {
      _Float16 hh = (_Float16)xs[e];
      _Float16 ll = (_Float16)(xs[e] - (float)hh);
      unsigned short uh = __builtin_bit_cast(unsigned short, hh);
      unsigned short ul = __builtin_bit_cast(unsigned short, ll);
      out[e] = (int)uh | ((int)ul << 16);
    }
    int4 r; r.x = out[0]; r.y = out[1]; r.z = out[2]; r.w = out[3];
    return r;
  };

  auto writeL = [&](int buf, SReg8& s) {
#pragma unroll
    for (int j = 0; j < 8; ++j)
      *reinterpret_cast<int4*>(&lA[buf][wOf[j]]) = cvt4(s.a[j]);
#pragma unroll
    for (int j = 0; j < 8; ++j)
      *reinterpret_cast<int4*>(&lB[buf][wOf[j]]) = s.b[j];
  };

  auto compute = [&](int buf) {
#pragma unroll
    for (int ks = 0; ks < 4; ++ks) {
      int s = ks * 4 + g;
      f16x8 af[4], bv[4];
#pragma unroll
      for (int m = 0; m < 4; ++m) {
        int row = wr * 64 + m * 16 + fr;
        af[m] = *reinterpret_cast<const f16x8*>(&lA[buf][s * 1024 + swz(row, s) * 8]);
      }
#pragma unroll
      for (int n = 0; n < 4; ++n) {
        int row = wc * 64 + n * 16 + fr;
        bv[n] = *reinterpret_cast<const f16x8*>(&lB[buf][s * 1024 + swz(row, s) * 8]);
      }
#pragma unroll
      for (int m = 0; m < 4; ++m)
#pragma unroll
        for (int n = 0; n < 4; ++n)
          acc[m][n] = __builtin_amdgcn_mfma_f32_16x16x32_f16(af[m], bv[n], acc[m][n], 0, 0, 0);
    }
  };

  SReg8 SA, SB;
  loadR(SA, 0); loadR(SB, 1);
  writeL(0, SA);
  loadR(SA, 2);
  __syncthreads();

  for (int t = 0; t < 4; t += 2) {
    writeL(1, SB); loadR(SB, t + 3);
    compute(0); __syncthreads();
    writeL(0, SA); loadR(SA, t + 4);
    compute(1); __syncthreads();
  }
  writeL(1, SB); loadR(SB, 7);   // write 5, load 7
  compute(0); __syncthreads();   // compute 4
  writeL(0, SA);                 // write 6
  compute(1); __syncthreads();   // compute 5
  writeL(1, SB);                 // write 7
  compute(0); __syncthreads();   // compute 6
  compute(1);                    // compute 7

#pragma unroll
  for (int m = 0; m < 4; ++m) {
#pragma unroll
    for (int n = 0; n < 4; ++n) {
      int row = m0 + wr * 64 + m * 16 + g * 4;   // C/D: row=(lane>>4)*4+reg
      int col = n0 + wc * 64 + n * 16 + fr;      //      col=lane&15
#pragma unroll
      for (int r = 0; r < 4; ++r)
        Wh[(size_t)(row + r) * OUT_F + col] = acc[m][n][r];
    }
  }
}

// ---- rank: 32 lanes/key, 1024 blocks (4/CU), aligned padded LDS, unsigned keys ----
__global__ __launch_bounds__(256) void k_rank(const float* __restrict__ s2,
                                              float* __restrict__ s2s, int* __restrict__ perm,
                                              float* __restrict__ eaA, float* __restrict__ ebA) {
  __shared__ unsigned int ls[32 * 260];  // part p at ls[p*260+i]; addr 4*(65p+q) -> b128 ok
  int t = threadIdx.x;
#pragma unroll
  for (int k = 0; k < 8; ++k) {
    int q = t + 256 * k;                  // float4 index 0..2047
    int p = q >> 6, i = q & 63;
    uint4 u = reinterpret_cast<const uint4*>(s2)[q];
    uint4 v;
    v.x = (u.x >> 31) ? ~u.x : (u.x | 0x80000000u);
    v.y = (u.y >> 31) ? ~u.y : (u.y | 0x80000000u);
    v.z = (u.z >> 31) ? ~u.z : (u.z | 0x80000000u);
    v.w = (u.w >> 31) ? ~u.w : (u.w | 0x80000000u);
    *reinterpret_cast<uint4*>(&ls[p * 260 + i * 4]) = v;
  }
  __syncthreads();

  int ki = blockIdx.x * 8 + (t >> 5);    // 1024 blocks x 8 keys
  int part = t & 31;                     // 32 lanes share one key
  unsigned int key = ls[(ki >> 8) * 260 + (ki & 255)];
  int rank = 0;
  const int base = part * 260;
  int jbase = part * 256;
#pragma unroll 8
  for (int q = 0; q < 64; ++q) {
    uint4 v = *reinterpret_cast<const uint4*>(&ls[base + q * 4]);
    int j = jbase + q * 4;
    rank += (v.x < key) || (v.x == key && (j + 0) < ki);
    rank += (v.y < key) || (v.y == key && (j + 1) < ki);
    rank += (v.z < key) || (v.z == key && (j + 2) < ki);
    rank += (v.w < key) || (v.w == key && (j + 3) < ki);
  }
  rank += __shfl_xor(rank, 1);
  rank += __shfl_xor(rank, 2);
  rank += __shfl_xor(rank, 4);
  rank += __shfl_xor(rank, 8);
  rank += __shfl_xor(rank, 16);
  if (part == 0) {
    float kf = s2[ki];
    s2s[rank] = kf; perm[rank] = ki;
    eaA[rank] = expf(kf); ebA[rank] = expf(LRALPHA * kf);
  }
}

// ---- passA: gather partials -> TRANSPOSED chunk sums [col][chunk];
//      block (NCH,0): scalar scans fold (R15-verified) ----
__global__ __launch_bounds__(256) void k_passA(const float* __restrict__ Wh,
                                               const float* __restrict__ eaA,
                                               const float* __restrict__ ebA,
                                               const int* __restrict__ perm,
                                               float* __restrict__ chunkA, float* __restrict__ chunkB,
                                               float* __restrict__ sufa, float* __restrict__ preb) {
  int t = threadIdx.x;
  __shared__ float spa[4][64], spb[4][64];
  if (blockIdx.x == NCH) {
    if (blockIdx.y != 0) return;
    int lane = t & 63, w = t >> 6;
    float sa = 0.f, sb = 0.f;
#pragma unroll
    for (int q = 0; q < 8; ++q) {
      float4 va = reinterpret_cast<const float4*>(eaA)[t * 8 + q];
      float4 vb = reinterpret_cast<const float4*>(ebA)[t * 8 + q];
      sa += va.x + va.y + va.z + va.w;
      sb += vb.x + vb.y + vb.z + vb.w;
    }
    float pb = sb;
#pragma unroll
    for (int off = 1; off < 64; off <<= 1) { float v = __shfl_up(pb, off); if (lane >= off) pb += v; }
    float pa = sa;
#pragma unroll
    for (int off = 1; off < 64; off <<= 1) { float v = __shfl_down(pa, off); if (lane < 64 - off) pa += v; }
    __shared__ float wtb[4], wta[4];
    if (lane == 63) wtb[w] = pb;
    if (lane == 0)  wta[w] = pa;
    __syncthreads();
    if (t == 0) {
      float rb = 0.f;
      for (int i = 0; i < 4; ++i) { float tmp = wtb[i]; wtb[i] = rb; rb += tmp; }
      float ra = 0.f;
      for (int i = 3; i >= 0; --i) { float tmp = wta[i]; wta[i] = ra; ra += tmp; }
    }
    __syncthreads();
    float run = wtb[w] + (pb - sb);
#pragma unroll
    for (int q = 0; q < 8; ++q) {
      float4 vb = reinterpret_cast<const float4*>(ebA)[t * 8 + q];
      float e4[4] = {vb.x, vb.y, vb.z, vb.w};
#pragma unroll
      for (int e = 0; e < 4; ++e) { preb[t * 32 + q * 4 + e] = run; run += e4[e]; }
    }
    if (t == 255) preb[NR] = run;
    run = wta[w] + (pa - sa);
#pragma unroll
    for (int q = 7; q >= 0; --q) {
      float4 va = reinterpret_cast<const float4*>(eaA)[t * 8 + q];
      float e4[4] = {va.x, va.y, va.z, va.w};
#pragma unroll
      for (int e = 3; e >= 0; --e) { run += e4[e]; sufa[t * 32 + q * 4 + e] = run; }
    }
    if (t == 0) sufa[NR] = 0.f;
    return;
  }
  int chunk = blockIdx.x, cb = blockIdx.y;
  int lane = t & 63, g = t >> 6;
  int col = cb * 64 + lane;
  int rg = chunk * CHR + g * 16;
  float v[16];
#pragma unroll
  for (int j = 0; j < 16; ++j)
    v[j] = Wh[(size_t)perm[rg + j] * OUT_F + col];
  float pa = 0.f, pb = 0.f;
#pragma unroll
  for (int j = 0; j < 16; ++j) {
    float ea = eaA[rg + j], eb = ebA[rg + j];
    pa += ea * v[j]; pb += eb * v[j];
  }
  spa[g][lane] = pa; spb[g][lane] = pb;
  __syncthreads();
  if (g == 0) {
    chunkA[(size_t)col * NCH + chunk] = spa[0][lane] + spa[1][lane] + spa[2][lane] + spa[3][lane];
    chunkB[(size_t)col * NCH + chunk] = spb[0][lane] + spb[1][lane] + spb[2][lane] + spb[3][lane];
  }
}

// ---- passB: wave-per-column shfl scan of 128 chunk sums -> bases [c][col] ----
__global__ __launch_bounds__(256) void k_passB(const float* __restrict__ chunkA,
                                               const float* __restrict__ chunkB,
                                               float* __restrict__ baseA, float* __restrict__ baseB) {
  int lane = threadIdx.x & 63, w = threadIdx.x >> 6;
  int col = blockIdx.x * 4 + w;           // 128 blocks x 4 waves = 512 cols
  float xa0 = chunkA[(size_t)col * NCH + lane];
  float xa1 = chunkA[(size_t)col * NCH + 64 + lane];
  float yb0 = chunkB[(size_t)col * NCH + lane];
  float yb1 = chunkB[(size_t)col * NCH + 64 + lane];

  float p0 = yb0, p1 = yb1;
#pragma unroll
  for (int off = 1; off < 64; off <<= 1) {
    float v0 = __shfl_up(p0, off); if (lane >= off) p0 += v0;
    float v1 = __shfl_up(p1, off); if (lane >= off) p1 += v1;
  }
  float T0 = __shfl(p0, 63);
  p1 += T0;
  baseB[(size_t)lane * OUT_F + col] = p0 - yb0;
  baseB[(size_t)(64 + lane) * OUT_F + col] = p1 - yb1;

  float s0 = xa0, s1 = xa1;
#pragma unroll
  for (int off = 1; off < 64; off <<= 1) {
    float v1 = __shfl_down(s1, off); if (lane < 64 - off) s1 += v1;
    float v0 = __shfl_down(s0, off); if (lane < 64 - off) s0 += v0;
  }
  float S1 = __shfl(s1, 0);
  s0 += S1;
  baseA[(size_t)lane * OUT_F + col] = s0 - xa0;
  baseA[(size_t)(64 + lane) * OUT_F + col] = s1 - xa1;
}

// ---- passC: FLOAT4-WIDE scans (R19-verified: 1KB/wave loads AND stores) ----
__global__ __launch_bounds__(512, 1) void k_passC(const float* __restrict__ Wh,
                                                  const float* __restrict__ eaA,
                                                  const float* __restrict__ ebA,
                                                  const int* __restrict__ perm,
                                                  const float* __restrict__ baseA,
                                                  const float* __restrict__ baseB,
                                                  float* __restrict__ SufA, float* __restrict__ PreB) {
  int chunk = blockIdx.x, cb = blockIdx.y;
  int t = threadIdx.x;
  int lane = t & 63, g = t >> 6;          // 8 waves, 8 rows each
  int colb = cb * 256 + lane * 4;
  int rg = chunk * CHR + g * 8;
  float4 v4[8];
  float ea[8], eb[8];
#pragma unroll
  for (int j = 0; j < 8; ++j)
    v4[j] = *reinterpret_cast<const float4*>(&Wh[(size_t)perm[rg + j] * OUT_F + colb]);
#pragma unroll
  for (int j = 0; j < 8; ++j) { ea[j] = eaA[rg + j]; eb[j] = ebA[rg + j]; }

  float4 pa = {0.f, 0.f, 0.f, 0.f}, pb = {0.f, 0.f, 0.f, 0.f};
#pragma unroll
  for (int j = 0; j < 8; ++j) {
    pa.x += ea[j] * v4[j].x; pa.y += ea[j] * v4[j].y; pa.z += ea[j] * v4[j].z; pa.w += ea[j] * v4[j].w;
    pb.x += eb[j] * v4[j].x; pb.y += eb[j] * v4[j].y; pb.z += eb[j] * v4[j].z; pb.w += eb[j] * v4[j].w;
  }
  __shared__ float4 spa[8][64], spb[8][64];
  spa[g][lane] = pa; spb[g][lane] = pb;
  __syncthreads();

  float4 bA = *reinterpret_cast<const float4*>(&baseA[(size_t)chunk * OUT_F + colb]);
  float4 bB = *reinterpret_cast<const float4*>(&baseB[(size_t)chunk * OUT_F + colb]);
#pragma unroll
  for (int g2 = 0; g2 < 8; ++g2) {
    if (g2 > g) {
      float4 q = spa[g2][lane];
      bA.x += q.x; bA.y += q.y; bA.z += q.z; bA.w += q.w;
    }
    if (g2 < g) {
      float4 q = spb[g2][lane];
      bB.x += q.x; bB.y += q.y; bB.z += q.z; bB.w += q.w;
    }
  }

  float4 acc = {0.f, 0.f, 0.f, 0.f};
#pragma unroll
  for (int j = 7; j >= 0; --j) {          // suffix incl.
    acc.x += ea[j] * v4[j].x; acc.y += ea[j] * v4[j].y;
    acc.z += ea[j] * v4[j].z; acc.w += ea[j] * v4[j].w;
    float4 o = {acc.x + bA.x, acc.y + bA.y, acc.z + bA.z, acc.w + bA.w};
    *reinterpret_cast<float4*>(&SufA[(size_t)(rg + j) * OUT_F + colb]) = o;
  }
  acc = {0.f, 0.f, 0.f, 0.f};
#pragma unroll
  for (int j = 0; j < 8; ++j) {           // prefix excl.
    float4 o = {acc.x + bB.x, acc.y + bB.y, acc.z + bB.z, acc.w + bB.w};
    *reinterpret_cast<float4*>(&PreB[(size_t)(rg + j) * OUT_F + colb]) = o;
    acc.x += eb[j] * v4[j].x; acc.y += eb[j] * v4[j].y;
    acc.z += eb[j] * v4[j].z; acc.w += eb[j] * v4[j].w;
  }
  if (chunk == NCH - 1) {
    if (g == 0) {
      float4 z = {0.f, 0.f, 0.f, 0.f};
      *reinterpret_cast<float4*>(&SufA[(size_t)NR * OUT_F + colb]) = z;
    }
    if (g == 7) {
      float4 o = {acc.x + bB.x, acc.y + bB.y, acc.z + bB.z, acc.w + bB.w};
      *reinterpret_cast<float4*>(&PreB[(size_t)NR * OUT_F + colb]) = o;
    }
  }
}

// ---- per-row: binary search threshold rank, combine, elu ----
__global__ __launch_bounds__(256) void k_final(const float* __restrict__ s1,
                                               const float* __restrict__ s2s,
                                               const float* __restrict__ sufa,
                                               const float* __restrict__ preb,
                                               const float* __restrict__ SufA,
                                               const float* __restrict__ PreB,
                                               float* __restrict__ out) {
  int row = blockIdx.x * 4 + (threadIdx.x >> 6);
  int lane = threadIdx.x & 63;
  float sv = s1[row];
  float t = -sv;
  int lo = 0, hi = NR;
  while (lo < hi) {  // first index with s2s[idx] > t
    int mid = (lo + hi) >> 1;
    if (s2s[mid] > t) hi = mid; else lo = mid + 1;
  }
  float E1 = expf(sv), E1a = expf(LRALPHA * sv);
  float Z = E1 * sufa[lo] + E1a * preb[lo];
  const float* rA = SufA + (size_t)lo * OUT_F;
  const float* rB = PreB + (size_t)lo * OUT_F;
#pragma unroll
  for (int e = 0; e < 8; ++e) {
    int kc = e * 64 + lane;
    float num = E1 * rA[kc] + E1a * rB[kc];
    float h = num / Z;
    out[(size_t)row * OUT_F + kc] = (h > 0.f) ? h : expm1f(h);
  }
}

extern "C" void kernel_launch(void* const* d_in, const int* in_sizes, int n_in,
                              void* d_out, int out_size, void* d_ws, size_t ws_size,
                              hipStream_t stream) {
  (void)in_sizes; (void)n_in; (void)out_size; (void)ws_size;
  const float* feat_edge   = (const float*)d_in[0];
  const float* feat_edge_a = (const float*)d_in[1];
  const float* feat_node_a = (const float*)d_in[2];
  const float* weight      = (const float*)d_in[3];
  const float* att         = (const float*)d_in[4];
  float* out = (float*)d_out;

  char* ws = (char*)d_ws;
  size_t off = 0;
  auto alloc = [&](size_t bytes) { size_t o = off; off += (bytes + 255) & ~(size_t)255; return o; };

  float* Wh = (float*)(ws + alloc((size_t)NR * OUT_F * 4));           // 16.78 MB
  size_t regionOff = alloc((size_t)(NR + 1) * OUT_F * 4 * 2);          // 33.56 MB
  float* SufA = (float*)(ws + regionOff);
  float* PreB = (float*)(ws + regionOff + (size_t)(NR + 1) * OUT_F * 4);
  short* B3t  = (short*)(ws + regionOff);                              // 1.05 MB

  float* s1   = (float*)(ws + alloc(NR * 4));
  float* s2   = (float*)(ws + alloc(NR * 4));
  float* s2s  = (float*)(ws + alloc(NR * 4));
  int*   perm = (int*)  (ws + alloc(NR * 4));
  float* sufa = (float*)(ws + alloc((NR + 1) * 4));
  float* preb = (float*)(ws + alloc((NR + 1) * 4));
  float* eaA  = (float*)(ws + alloc(NR * 4));
  float* ebA  = (float*)(ws + alloc(NR * 4));
  float* chA  = (float*)(ws + alloc(NCH * OUT_F * 4));
  float* chB  = (float*)(ws + alloc(NCH * OUT_F * 4));
  float* bsA  = (float*)(ws + alloc(NCH * OUT_F * 4));
  float* bsB  = (float*)(ws + alloc(NCH * OUT_F * 4));

  k_prep<<<4096 + 1024, 256, 0, stream>>>(feat_edge, feat_edge_a, att, weight, s1, s2, B3t);
  k_gemm<<<256, 256, 0, stream>>>(feat_node_a, B3t, Wh);
  k_rank<<<NR / 8, 256, 0, stream>>>(s2, s2s, perm, eaA, ebA);
  k_passA<<<dim3(NCH + 1, 8), 256, 0, stream>>>(Wh, eaA, ebA, perm, chA, chB, sufa, preb);
  k_passB<<<NCH, 256, 0, stream>>>(chA, chB, bsA, bsB);
  k_passC<<<dim3(NCH, 2), 512, 0, stream>>>(Wh, eaA, ebA, perm, bsA, bsB, SufA, PreB);
  k_final<<<NR / 4, 256, 0, stream>>>(s1, s2s, sufa, preb, SufA, PreB, out);
}

// Round 21
// 76.854 us; speedup vs baseline: 1.1210x; 1.1210x over previous
//
#include <hip/hip_runtime.h>
#include <cstdint>
#include <cstddef>

#define LRALPHA 0.1f
static constexpr int NR = 8192;      // N and Na
static constexpr int EF = 256;
static constexpr int IN_F = 512;
static constexpr int OUT_F = 512;
static constexpr int KP2 = 1024;     // fp16 split-2, k'-interleaved [ah,al]
static constexpr int NCH = 128;      // chunks for column scans
static constexpr int CHR = 64;       // rows per chunk (NCH*CHR = 8192)

typedef __attribute__((ext_vector_type(8))) _Float16 f16x8;
typedef __attribute__((ext_vector_type(4))) float f32x4;

// ---- fused prep: s1/s2 dots (blocks 0..4095) + B pack ----
__global__ __launch_bounds__(256) void k_prep(const float* __restrict__ feat_edge,
                                              const float* __restrict__ feat_edge_a,
                                              const float* __restrict__ att,
                                              const float* __restrict__ W,
                                              float* __restrict__ s1,
                                              float* __restrict__ s2,
                                              short* __restrict__ B3t) {
  int b = blockIdx.x;
  if (b < 4096) {
    int vrow = b * 4 + (threadIdx.x >> 6);
    int lane = threadIdx.x & 63;
    const float* feat; const float* av; float* outp; int row;
    if (vrow < NR) { row = vrow; feat = feat_edge; av = att; outp = s1; }
    else { row = vrow - NR; feat = feat_edge_a; av = att + EF; outp = s2; }
    float4 f = reinterpret_cast<const float4*>(feat + (size_t)row * EF)[lane];
    float4 a = reinterpret_cast<const float4*>(av)[lane];
    float d = f.x * a.x + f.y * a.y + f.z * a.z + f.w * a.w;
#pragma unroll
    for (int off = 32; off > 0; off >>= 1) d += __shfl_xor(d, off);
    if (lane == 0) outp[row] = d;
  } else {
    int i = (b - 4096) * 256 + threadIdx.x;  // < 512*512
    int n = i >> 9, k = i & 511;
    float x = W[(size_t)k * OUT_F + n];
    _Float16 h = (_Float16)x;
    unsigned short u = __builtin_bit_cast(unsigned short, h);
    unsigned int w = (unsigned int)u | ((unsigned int)u << 16);
    *reinterpret_cast<unsigned int*>(B3t + (size_t)n * KP2 + 2 * k) = w;
  }
}

// ---- Wh = split2(A) @ B3t^T : 128x128 tile, BK'=64, dbuf 64KB, 16 iters (R19-best) ----
struct SReg4 { float4 a0, a1, a2, a3; int4 b0, b1, b2, b3; };

__device__ __forceinline__ int swz(int row, int slot) {
  return (row & ~7) | ((row & 7) ^ (slot & 7));
}

__global__ __launch_bounds__(256, 1) void k_gemm(const float* __restrict__ A,
                                                 const short* __restrict__ B3t,
                                                 float* __restrict__ Wh) {
  // per buffer: [slot=k'/8 (8)][row (128)][8 f16] = 8192 shorts = 16KB; A+B dbuf = 64KB
  __shared__ short lA[2][8192];
  __shared__ short lB[2][8192];
  const int tid = threadIdx.x;
  const int wid = tid >> 6, lane = tid & 63;
  const int wr = wid >> 1, wc = wid & 1;
  int bid = blockIdx.x;                       // 0..255
  int xcd = bid & 7, loc = bid >> 3;          // 32 tiles per XCD
  int mb = (xcd << 3) | (loc >> 2), nb = loc & 3;   // XCD band: 2MB A + 1MB B L2-resident
  const int m0 = mb * 128, n0 = nb * 128;
  const int fr = lane & 15, g = lane >> 4;

  const int srow = tid >> 1, h = tid & 1;
  const float* gA = A + (size_t)(m0 + srow) * IN_F + h * 16;
  const short* gB = B3t + (size_t)(n0 + srow) * KP2 + h * 32;
  int wOf[4];
#pragma unroll
  for (int j = 0; j < 4; ++j) {
    int s = h * 4 + j;
    wOf[j] = s * 1024 + swz(srow, s) * 8;
  }

  f32x4 acc[4][4] = {};

  auto loadR = [&](SReg4& s, int t) {
    const float* pa = gA + t * 32;
    s.a0 = *reinterpret_cast<const float4*>(pa);
    s.a1 = *reinterpret_cast<const float4*>(pa + 4);
    s.a2 = *reinterpret_cast<const float4*>(pa + 8);
    s.a3 = *reinterpret_cast<const float4*>(pa + 12);
    const short* pb = gB + t * 64;
    s.b0 = *reinterpret_cast<const int4*>(pb);
    s.b1 = *reinterpret_cast<const int4*>(pb + 8);
    s.b2 = *reinterpret_cast<const int4*>(pb + 16);
    s.b3 = *reinterpret_cast<const int4*>(pb + 24);
  };

  auto cvt4 = [](float4 p) -> int4 {  // 4 f32 -> 4 dwords of [ah | al]
    float xs[4] = {p.x, p.y, p.z, p.w};
    int out[4];
#pragma unroll
    for (int e = 0; e < 4; ++e) {
      _Float16 hh = (_Float16)xs[e];
      _Float16 ll = (_Float16)(xs[e] - (float)hh);
      unsigned short uh = __builtin_bit_cast(unsigned short, hh);
      unsigned short ul = __builtin_bit_cast(unsigned short, ll);
      out[e] = (int)uh | ((int)ul << 16);
    }
    int4 r; r.x = out[0]; r.y = out[1]; r.z = out[2]; r.w = out[3];
    return r;
  };

  auto writeL = [&](int buf, SReg4& s) {
    *reinterpret_cast<int4*>(&lA[buf][wOf[0]]) = cvt4(s.a0);
    *reinterpret_cast<int4*>(&lA[buf][wOf[1]]) = cvt4(s.a1);
    *reinterpret_cast<int4*>(&lA[buf][wOf[2]]) = cvt4(s.a2);
    *reinterpret_cast<int4*>(&lA[buf][wOf[3]]) = cvt4(s.a3);
    *reinterpret_cast<int4*>(&lB[buf][wOf[0]]) = s.b0;
    *reinterpret_cast<int4*>(&lB[buf][wOf[1]]) = s.b1;
    *reinterpret_cast<int4*>(&lB[buf][wOf[2]]) = s.b2;
    *reinterpret_cast<int4*>(&lB[buf][wOf[3]]) = s.b3;
  };

  auto compute = [&](int buf) {
#pragma unroll
    for (int ks = 0; ks < 2; ++ks) {
      int s = ks * 4 + g;
      f16x8 af[4], bv[4];
#pragma unroll
      for (int m = 0; m < 4; ++m) {
        int row = wr * 64 + m * 16 + fr;
        af[m] = *reinterpret_cast<const f16x8*>(&lA[buf][s * 1024 + swz(row, s) * 8]);
      }
#pragma unroll
      for (int n = 0; n < 4; ++n) {
        int row = wc * 64 + n * 16 + fr;
        bv[n] = *reinterpret_cast<const f16x8*>(&lB[buf][s * 1024 + swz(row, s) * 8]);
      }
#pragma unroll
      for (int m = 0; m < 4; ++m)
#pragma unroll
        for (int n = 0; n < 4; ++n)
          acc[m][n] = __builtin_amdgcn_mfma_f32_16x16x32_f16(af[m], bv[n], acc[m][n], 0, 0, 0);
    }
  };

  SReg4 SA, SB;
  loadR(SA, 0); loadR(SB, 1);
  writeL(0, SA);
  loadR(SA, 2);
  __syncthreads();

  for (int t = 0; t < 12; t += 2) {
    writeL(1, SB); loadR(SB, t + 3);
    compute(0); __syncthreads();
    writeL(0, SA); loadR(SA, t + 4);
    compute(1); __syncthreads();
  }
  writeL(1, SB); loadR(SB, 15);
  compute(0); __syncthreads();
  writeL(0, SA);
  compute(1); __syncthreads();
  writeL(1, SB);
  compute(0); __syncthreads();
  compute(1);

#pragma unroll
  for (int m = 0; m < 4; ++m) {
#pragma unroll
    for (int n = 0; n < 4; ++n) {
      int row = m0 + wr * 64 + m * 16 + g * 4;   // C/D: row=(lane>>4)*4+reg
      int col = n0 + wc * 64 + n * 16 + fr;      //      col=lane&15
#pragma unroll
      for (int r = 0; r < 4; ++r)
        Wh[(size_t)(row + r) * OUT_F + col] = acc[m][n][r];
    }
  }
}

// ---- rank: 32 lanes/key, 1024 blocks (4/CU), aligned padded LDS, unsigned keys ----
__global__ __launch_bounds__(256) void k_rank(const float* __restrict__ s2,
                                              float* __restrict__ s2s, int* __restrict__ perm,
                                              float* __restrict__ eaA, float* __restrict__ ebA) {
  __shared__ unsigned int ls[32 * 260];  // part p at ls[p*260+i]; addr 4*(65p+q) -> b128 ok
  int t = threadIdx.x;
#pragma unroll
  for (int k = 0; k < 8; ++k) {
    int q = t + 256 * k;                  // float4 index 0..2047
    int p = q >> 6, i = q & 63;
    uint4 u = reinterpret_cast<const uint4*>(s2)[q];
    uint4 v;
    v.x = (u.x >> 31) ? ~u.x : (u.x | 0x80000000u);
    v.y = (u.y >> 31) ? ~u.y : (u.y | 0x80000000u);
    v.z = (u.z >> 31) ? ~u.z : (u.z | 0x80000000u);
    v.w = (u.w >> 31) ? ~u.w : (u.w | 0x80000000u);
    *reinterpret_cast<uint4*>(&ls[p * 260 + i * 4]) = v;
  }
  __syncthreads();

  int ki = blockIdx.x * 8 + (t >> 5);    // 1024 blocks x 8 keys
  int part = t & 31;                     // 32 lanes share one key
  unsigned int key = ls[(ki >> 8) * 260 + (ki & 255)];
  int rank = 0;
  const int base = part * 260;
  int jbase = part * 256;
#pragma unroll 8
  for (int q = 0; q < 64; ++q) {
    uint4 v = *reinterpret_cast<const uint4*>(&ls[base + q * 4]);
    int j = jbase + q * 4;
    rank += (v.x < key) || (v.x == key && (j + 0) < ki);
    rank += (v.y < key) || (v.y == key && (j + 1) < ki);
    rank += (v.z < key) || (v.z == key && (j + 2) < ki);
    rank += (v.w < key) || (v.w == key && (j + 3) < ki);
  }
  rank += __shfl_xor(rank, 1);
  rank += __shfl_xor(rank, 2);
  rank += __shfl_xor(rank, 4);
  rank += __shfl_xor(rank, 8);
  rank += __shfl_xor(rank, 16);
  if (part == 0) {
    float kf = s2[ki];
    s2s[rank] = kf; perm[rank] = ki;
    eaA[rank] = expf(kf); ebA[rank] = expf(LRALPHA * kf);
  }
}

// ---- passA: FLOAT4-wide gather (grid (NCH+1,2), lane owns 4 cols, 4 grp x 16 rows);
//      transposed chunk sums [col][chunk]; block (NCH,0): scalar scans fold ----
__global__ __launch_bounds__(256, 1) void k_passA(const float* __restrict__ Wh,
                                                  const float* __restrict__ eaA,
                                                  const float* __restrict__ ebA,
                                                  const int* __restrict__ perm,
                                                  float* __restrict__ chunkA, float* __restrict__ chunkB,
                                                  float* __restrict__ sufa, float* __restrict__ preb) {
  int t = threadIdx.x;
  if (blockIdx.x == NCH) {
    if (blockIdx.y != 0) return;
    int lane = t & 63, w = t >> 6;
    float sa = 0.f, sb = 0.f;
#pragma unroll
    for (int q = 0; q < 8; ++q) {
      float4 va = reinterpret_cast<const float4*>(eaA)[t * 8 + q];
      float4 vb = reinterpret_cast<const float4*>(ebA)[t * 8 + q];
      sa += va.x + va.y + va.z + va.w;
      sb += vb.x + vb.y + vb.z + vb.w;
    }
    float pb = sb;
#pragma unroll
    for (int off = 1; off < 64; off <<= 1) { float v = __shfl_up(pb, off); if (lane >= off) pb += v; }
    float pa = sa;
#pragma unroll
    for (int off = 1; off < 64; off <<= 1) { float v = __shfl_down(pa, off); if (lane < 64 - off) pa += v; }
    __shared__ float wtb[4], wta[4];
    if (lane == 63) wtb[w] = pb;
    if (lane == 0)  wta[w] = pa;
    __syncthreads();
    if (t == 0) {
      float rb = 0.f;
      for (int i = 0; i < 4; ++i) { float tmp = wtb[i]; wtb[i] = rb; rb += tmp; }
      float ra = 0.f;
      for (int i = 3; i >= 0; --i) { float tmp = wta[i]; wta[i] = ra; ra += tmp; }
    }
    __syncthreads();
    float run = wtb[w] + (pb - sb);
#pragma unroll
    for (int q = 0; q < 8; ++q) {
      float4 vb = reinterpret_cast<const float4*>(ebA)[t * 8 + q];
      float e4[4] = {vb.x, vb.y, vb.z, vb.w};
#pragma unroll
      for (int e = 0; e < 4; ++e) { preb[t * 32 + q * 4 + e] = run; run += e4[e]; }
    }
    if (t == 255) preb[NR] = run;
    run = wta[w] + (pa - sa);
#pragma unroll
    for (int q = 7; q >= 0; --q) {
      float4 va = reinterpret_cast<const float4*>(eaA)[t * 8 + q];
      float e4[4] = {va.x, va.y, va.z, va.w};
#pragma unroll
      for (int e = 3; e >= 0; --e) { run += e4[e]; sufa[t * 32 + q * 4 + e] = run; }
    }
    if (t == 0) sufa[NR] = 0.f;
    return;
  }
  int chunk = blockIdx.x, cb = blockIdx.y;
  int lane = t & 63, g = t >> 6;          // 4 groups x 16 rows
  int colb = cb * 256 + lane * 4;
  int rg = chunk * CHR + g * 16;
  float4 v4[16];
#pragma unroll
  for (int j = 0; j < 16; ++j)
    v4[j] = *reinterpret_cast<const float4*>(&Wh[(size_t)perm[rg + j] * OUT_F + colb]);
  float4 pa = {0.f, 0.f, 0.f, 0.f}, pb = {0.f, 0.f, 0.f, 0.f};
#pragma unroll
  for (int j = 0; j < 16; ++j) {
    float ea = eaA[rg + j], eb = ebA[rg + j];
    pa.x += ea * v4[j].x; pa.y += ea * v4[j].y; pa.z += ea * v4[j].z; pa.w += ea * v4[j].w;
    pb.x += eb * v4[j].x; pb.y += eb * v4[j].y; pb.z += eb * v4[j].z; pb.w += eb * v4[j].w;
  }
  __shared__ float4 spa[4][64], spb[4][64];
  spa[g][lane] = pa; spb[g][lane] = pb;
  __syncthreads();
  if (g == 0) {
    float4 A = spa[0][lane], B = spb[0][lane];
#pragma unroll
    for (int g2 = 1; g2 < 4; ++g2) {
      float4 qa = spa[g2][lane], qb = spb[g2][lane];
      A.x += qa.x; A.y += qa.y; A.z += qa.z; A.w += qa.w;
      B.x += qb.x; B.y += qb.y; B.z += qb.z; B.w += qb.w;
    }
    chunkA[(size_t)(colb + 0) * NCH + chunk] = A.x;
    chunkA[(size_t)(colb + 1) * NCH + chunk] = A.y;
    chunkA[(size_t)(colb + 2) * NCH + chunk] = A.z;
    chunkA[(size_t)(colb + 3) * NCH + chunk] = A.w;
    chunkB[(size_t)(colb + 0) * NCH + chunk] = B.x;
    chunkB[(size_t)(colb + 1) * NCH + chunk] = B.y;
    chunkB[(size_t)(colb + 2) * NCH + chunk] = B.z;
    chunkB[(size_t)(colb + 3) * NCH + chunk] = B.w;
  }
}

// ---- passB: wave-per-column shfl scan of 128 chunk sums -> bases [c][col] ----
__global__ __launch_bounds__(256) void k_passB(const float* __restrict__ chunkA,
                                               const float* __restrict__ chunkB,
                                               float* __restrict__ baseA, float* __restrict__ baseB) {
  int lane = threadIdx.x & 63, w = threadIdx.x >> 6;
  int col = blockIdx.x * 4 + w;           // 128 blocks x 4 waves = 512 cols
  float xa0 = chunkA[(size_t)col * NCH + lane];
  float xa1 = chunkA[(size_t)col * NCH + 64 + lane];
  float yb0 = chunkB[(size_t)col * NCH + lane];
  float yb1 = chunkB[(size_t)col * NCH + 64 + lane];

  float p0 = yb0, p1 = yb1;
#pragma unroll
  for (int off = 1; off < 64; off <<= 1) {
    float v0 = __shfl_up(p0, off); if (lane >= off) p0 += v0;
    float v1 = __shfl_up(p1, off); if (lane >= off) p1 += v1;
  }
  float T0 = __shfl(p0, 63);
  p1 += T0;
  baseB[(size_t)lane * OUT_F + col] = p0 - yb0;
  baseB[(size_t)(64 + lane) * OUT_F + col] = p1 - yb1;

  float s0 = xa0, s1 = xa1;
#pragma unroll
  for (int off = 1; off < 64; off <<= 1) {
    float v1 = __shfl_down(s1, off); if (lane < 64 - off) s1 += v1;
    float v0 = __shfl_down(s0, off); if (lane < 64 - off) s0 += v0;
  }
  float S1 = __shfl(s1, 0);
  s0 += S1;
  baseA[(size_t)lane * OUT_F + col] = s0 - xa0;
  baseA[(size_t)(64 + lane) * OUT_F + col] = s1 - xa1;
}

// ---- passC: FLOAT4-WIDE scans (R19-verified: 1KB/wave loads AND stores) ----
__global__ __launch_bounds__(512, 1) void k_passC(const float* __restrict__ Wh,
                                                  const float* __restrict__ eaA,
                                                  const float* __restrict__ ebA,
                                                  const int* __restrict__ perm,
                                                  const float* __restrict__ baseA,
                                                  const float* __restrict__ baseB,
                                                  float* __restrict__ SufA, float* __restrict__ PreB) {
  int chunk = blockIdx.x, cb = blockIdx.y;
  int t = threadIdx.x;
  int lane = t & 63, g = t >> 6;          // 8 waves, 8 rows each
  int colb = cb * 256 + lane * 4;
  int rg = chunk * CHR + g * 8;
  float4 v4[8];
  float ea[8], eb[8];
#pragma unroll
  for (int j = 0; j < 8; ++j)
    v4[j] = *reinterpret_cast<const float4*>(&Wh[(size_t)perm[rg + j] * OUT_F + colb]);
#pragma unroll
  for (int j = 0; j < 8; ++j) { ea[j] = eaA[rg + j]; eb[j] = ebA[rg + j]; }

  float4 pa = {0.f, 0.f, 0.f, 0.f}, pb = {0.f, 0.f, 0.f, 0.f};
#pragma unroll
  for (int j = 0; j < 8; ++j) {
    pa.x += ea[j] * v4[j].x; pa.y += ea[j] * v4[j].y; pa.z += ea[j] * v4[j].z; pa.w += ea[j] * v4[j].w;
    pb.x += eb[j] * v4[j].x; pb.y += eb[j] * v4[j].y; pb.z += eb[j] * v4[j].z; pb.w += eb[j] * v4[j].w;
  }
  __shared__ float4 spa[8][64], spb[8][64];
  spa[g][lane] = pa; spb[g][lane] = pb;
  __syncthreads();

  float4 bA = *reinterpret_cast<const float4*>(&baseA[(size_t)chunk * OUT_F + colb]);
  float4 bB = *reinterpret_cast<const float4*>(&baseB[(size_t)chunk * OUT_F + colb]);
#pragma unroll
  for (int g2 = 0; g2 < 8; ++g2) {
    if (g2 > g) {
      float4 q = spa[g2][lane];
      bA.x += q.x; bA.y += q.y; bA.z += q.z; bA.w += q.w;
    }
    if (g2 < g) {
      float4 q = spb[g2][lane];
      bB.x += q.x; bB.y += q.y; bB.z += q.z; bB.w += q.w;
    }
  }

  float4 acc = {0.f, 0.f, 0.f, 0.f};
#pragma unroll
  for (int j = 7; j >= 0; --j) {          // suffix incl.
    acc.x += ea[j] * v4[j].x; acc.y += ea[j] * v4[j].y;
    acc.z += ea[j] * v4[j].z; acc.w += ea[j] * v4[j].w;
    float4 o = {acc.x + bA.x, acc.y + bA.y, acc.z + bA.z, acc.w + bA.w};
    *reinterpret_cast<float4*>(&SufA[(size_t)(rg + j) * OUT_F + colb]) = o;
  }
  acc = {0.f, 0.f, 0.f, 0.f};
#pragma unroll
  for (int j = 0; j < 8; ++j) {           // prefix excl.
    float4 o = {acc.x + bB.x, acc.y + bB.y, acc.z + bB.z, acc.w + bB.w};
    *reinterpret_cast<float4*>(&PreB[(size_t)(rg + j) * OUT_F + colb]) = o;
    acc.x += eb[j] * v4[j].x; acc.y += eb[j] * v4[j].y;
    acc.z += eb[j] * v4[j].z; acc.w += eb[j] * v4[j].w;
  }
  if (chunk == NCH - 1) {
    if (g == 0) {
      float4 z = {0.f, 0.f, 0.f, 0.f};
      *reinterpret_cast<float4*>(&SufA[(size_t)NR * OUT_F + colb]) = z;
    }
    if (g == 7) {
      float4 o = {acc.x + bB.x, acc.y + bB.y, acc.z + bB.z, acc.w + bB.w};
      *reinterpret_cast<float4*>(&PreB[(size_t)NR * OUT_F + colb]) = o;
    }
  }
}

// ---- per-row: binary search + FLOAT4-wide combine/elu (store-width law) ----
__global__ __launch_bounds__(256) void k_final(const float* __restrict__ s1,
                                               const float* __restrict__ s2s,
                                               const float* __restrict__ sufa,
                                               const float* __restrict__ preb,
                                               const float* __restrict__ SufA,
                                               const float* __restrict__ PreB,
                                               float* __restrict__ out) {
  int row = blockIdx.x * 4 + (threadIdx.x >> 6);
  int lane = threadIdx.x & 63;
  float sv = s1[row];
  float t = -sv;
  int lo = 0, hi = NR;
  while (lo < hi) {  // first index with s2s[idx] > t
    int mid = (lo + hi) >> 1;
    if (s2s[mid] > t) hi = mid; else lo = mid + 1;
  }
  float E1 = expf(sv), E1a = expf(LRALPHA * sv);
  float Z = E1 * sufa[lo] + E1a * preb[lo];
  float rz = 1.0f / Z;
  const float4* rA4 = reinterpret_cast<const float4*>(SufA + (size_t)lo * OUT_F);
  const float4* rB4 = reinterpret_cast<const float4*>(PreB + (size_t)lo * OUT_F);
  float4* o4 = reinterpret_cast<float4*>(out + (size_t)row * OUT_F);
#pragma unroll
  for (int e = 0; e < 2; ++e) {
    int c4 = e * 64 + lane;                // float4 index; 128 per row
    float4 a = rA4[c4], b = rB4[c4];
    float4 o;
    o.x = (E1 * a.x + E1a * b.x) * rz;
    o.y = (E1 * a.y + E1a * b.y) * rz;
    o.z = (E1 * a.z + E1a * b.z) * rz;
    o.w = (E1 * a.w + E1a * b.w) * rz;
    o.x = (o.x > 0.f) ? o.x : expm1f(o.x);
    o.y = (o.y > 0.f) ? o.y : expm1f(o.y);
    o.z = (o.z > 0.f) ? o.z : expm1f(o.z);
    o.w = (o.w > 0.f) ? o.w : expm1f(o.w);
    o4[c4] = o;
  }
}

extern "C" void kernel_launch(void* const* d_in, const int* in_sizes, int n_in,
                              void* d_out, int out_size, void* d_ws, size_t ws_size,
                              hipStream_t stream) {
  (void)in_sizes; (void)n_in; (void)out_size; (void)ws_size;
  const float* feat_edge   = (const float*)d_in[0];
  const float* feat_edge_a = (const float*)d_in[1];
  const float* feat_node_a = (const float*)d_in[2];
  const float* weight      = (const float*)d_in[3];
  const float* att         = (const float*)d_in[4];
  float* out = (float*)d_out;

  char* ws = (char*)d_ws;
  size_t off = 0;
  auto alloc = [&](size_t bytes) { size_t o = off; off += (bytes + 255) & ~(size_t)255; return o; };

  float* Wh = (float*)(ws + alloc((size_t)NR * OUT_F * 4));           // 16.78 MB
  size_t regionOff = alloc((size_t)(NR + 1) * OUT_F * 4 * 2);          // 33.56 MB
  float* SufA = (float*)(ws + regionOff);
  float* PreB = (float*)(ws + regionOff + (size_t)(NR + 1) * OUT_F * 4);
  short* B3t  = (short*)(ws + regionOff);                              // 1.05 MB

  float* s1   = (float*)(ws + alloc(NR * 4));
  float* s2   = (float*)(ws + alloc(NR * 4));
  float* s2s  = (float*)(ws + alloc(NR * 4));
  int*   perm = (int*)  (ws + alloc(NR * 4));
  float* sufa = (float*)(ws + alloc((NR + 1) * 4));
  float* preb = (float*)(ws + alloc((NR + 1) * 4));
  float* eaA  = (float*)(ws + alloc(NR * 4));
  float* ebA  = (float*)(ws + alloc(NR * 4));
  float* chA  = (float*)(ws + alloc(NCH * OUT_F * 4));
  float* chB  = (float*)(ws + alloc(NCH * OUT_F * 4));
  float* bsA  = (float*)(ws + alloc(NCH * OUT_F * 4));
  float* bsB  = (float*)(ws + alloc(NCH * OUT_F * 4));

  k_prep<<<4096 + 1024, 256, 0, stream>>>(feat_edge, feat_edge_a, att, weight, s1, s2, B3t);
  k_gemm<<<256, 256, 0, stream>>>(feat_node_a, B3t, Wh);
  k_rank<<<NR / 8, 256, 0, stream>>>(s2, s2s, perm, eaA, ebA);
  k_passA<<<dim3(NCH + 1, 2), 256, 0, stream>>>(Wh, eaA, ebA, perm, chA, chB, sufa, preb);
  k_passB<<<NCH, 256, 0, stream>>>(chA, chB, bsA, bsB);
  k_passC<<<dim3(NCH, 2), 512, 0, stream>>>(Wh, eaA, ebA, perm, bsA, bsB, SufA, PreB);
  k_final<<<NR / 4, 256, 0, stream>>>(s1, s2s, sufa, preb, SufA, PreB, out);
}